// Round 2
// baseline (349.611 us; speedup 1.0000x reference)
//
#include <hip/hip_runtime.h>
#include <stdint.h>

// Problem constants (from reference): B,T,X,E,H,L = 4096,32,256,32,512,2
#define B_SZ 4096
#define T_SZ 32
#define X_SZ 256
#define E_SZ 32
#define H_SZ 512
#define BM   64      // batch rows per block
// A-tile LDS row stride: 512 bf16 = 1024B, +16B pad -> conflict-free ds_read_b128
#define AROW 1040

typedef __attribute__((ext_vector_type(8))) short  short8;   // 8 bf16 = 4 VGPR
typedef __attribute__((ext_vector_type(4))) float  floatx4;

__device__ __forceinline__ unsigned short f2bf(float f) {
  unsigned u = __float_as_uint(f);
  u += 0x7fffu + ((u >> 16) & 1u);          // RNE (inputs finite, no NaN care)
  return (unsigned short)(u >> 16);
}
__device__ __forceinline__ unsigned pk2(float a, float b) {
  return (unsigned)f2bf(a) | ((unsigned)f2bf(b) << 16);
}

// ---------------------------------------------------------------------------
// Prep v2: coalesced. One block per (matrix, 32-row k-chunk).
//   blocks [0,288):   layer-1 cat matrix, e = b/9, kt = b%9. kt==0 -> W1t
//                     (mask folded), kt>=1 -> W1x rows (kt*32-32 ..).
//   blocks [288,1312): hidden, g=b-288, le=g>>4, kt=g&15, rows of Wh[le].
// Stage 32k x 512n fp32 -> bf16 LDS tile (row pitch 524 ushort = 262 dwords,
// even-dword so ds_write_b64 stays 8B-aligned; staging 2-way, gather 2-way
// bank aliasing = free). Then gather fragment units:
//   unit u: nb=u>>6, l=u&63 -> n=nb*16+(l&15), k0=(l>>4)*8; 8 bf16 along k.
// Output unit order identical to R0 prep, so mlp_kernel layout is unchanged.
// ---------------------------------------------------------------------------
#define LPITCH 524   // ushorts per LDS row

__global__ __launch_bounds__(256) void prep2_kernel(
    const float* __restrict__ W1t, const float* __restrict__ W1x,
    const int* __restrict__ masks, const float* __restrict__ Wh,
    uint4* __restrict__ wcat, uint4* __restrict__ whf) {
  __shared__ unsigned short lds[32 * LPITCH];   // 33536 B
  const int b = blockIdx.x, t = threadIdx.x;
  const bool l1 = b < 288;
  int e = 0, kt;
  const float* hbase = nullptr;
  if (l1) {
    e  = b / 9;
    kt = b - e * 9;
  } else {
    int g = b - 288;
    kt = g & 15;
    hbase = Wh + (size_t)(g >> 4) * H_SZ * H_SZ + (size_t)kt * 32 * H_SZ;
  }
#pragma unroll 4
  for (int p = 0; p < 16; ++p) {
    int f  = p * 256 + t;                 // float4 index within 32x512 tile
    int kk = f >> 7, n = (f & 127) * 4;
    float4 v;
    if (l1) {
      int k = kt * 32 + kk;
      if (k < T_SZ) {
        v = *(const float4*)(W1t + ((size_t)e * T_SZ + k) * H_SZ + n);
        float m = (float)masks[e * T_SZ + k];
        v.x *= m; v.y *= m; v.z *= m; v.w *= m;
      } else {
        v = *(const float4*)(W1x + ((size_t)e * X_SZ + (k - T_SZ)) * H_SZ + n);
      }
    } else {
      v = *(const float4*)(hbase + (size_t)kk * H_SZ + n);
    }
    *(uint2*)&lds[kk * LPITCH + n] = make_uint2(pk2(v.x, v.y), pk2(v.z, v.w));
  }
  __syncthreads();
  uint4* dst = l1 ? (wcat + ((size_t)e * 9 + kt) * 2048)
                  : (whf + (size_t)(b - 288) * 2048);
#pragma unroll 2
  for (int p = 0; p < 8; ++p) {
    int u  = p * 256 + t;
    int nb = u >> 6, l = u & 63;
    int n  = nb * 16 + (l & 15);
    int k0 = (l >> 4) * 8;
    unsigned d[4];
#pragma unroll
    for (int j = 0; j < 4; ++j) {
      unsigned lo = lds[(k0 + 2 * j)     * LPITCH + n];
      unsigned hi = lds[(k0 + 2 * j + 1) * LPITCH + n];
      d[j] = lo | (hi << 16);
    }
    dst[u] = make_uint4(d[0], d[1], d[2], d[3]);
  }
}

// ---------------------------------------------------------------------------
// Fused MLP: block = (64-row batch tile, expert e). 8 waves; wave w owns
// cols [64w,64w+64). acc 4x4 tiles of mfma_f32_16x16x32_bf16.
// A (activations) in LDS bf16, weights direct-from-global (fragment order).
// ---------------------------------------------------------------------------
__global__ __launch_bounds__(512, 4) void mlp_kernel(
    const float* __restrict__ theta, const float* __restrict__ x,
    const short8* __restrict__ wcat, const short8* __restrict__ whf,
    const float* __restrict__ b1, const float* __restrict__ a1,
    const float* __restrict__ bh, const float* __restrict__ ah,
    const float* __restrict__ Wo, const float* __restrict__ bo,
    float* __restrict__ out) {
  __shared__ __align__(16) char smA[BM * AROW];   // 66560 B
  const int tid = threadIdx.x;
  const int bid = blockIdx.x;
  const int r5  = bid & 31;
  const int e   = (r5 & 7) * 4 + (r5 >> 3);       // same-expert blocks -> same XCD (mod 8)
  const int m0  = (bid >> 5) * BM;
  const int w   = tid >> 6, l = tid & 63, l16 = l & 15, quad = l >> 4;

  // ---- stage A0 = [theta | x] as bf16 (mask folded into prepped W1t) ----
  {
    int r = tid >> 3, c = tid & 7;                // 8 threads per row
    float4 th = *(const float4*)(theta + (size_t)(m0 + r) * T_SZ + c * 4);
    *(uint2*)(smA + r * AROW + c * 8) = make_uint2(pk2(th.x, th.y), pk2(th.z, th.w));
    const float4* xp = (const float4*)(x + (size_t)(m0 + r) * X_SZ);
#pragma unroll
    for (int q = 0; q < 4; ++q) {
      int ch = q * 8 + c;                         // interleave: conflict-free banks
      float4 a = xp[ch * 2], bv = xp[ch * 2 + 1];
      *(uint4*)(smA + r * AROW + 64 + ch * 16) =
          make_uint4(pk2(a.x, a.y), pk2(a.z, a.w), pk2(bv.x, bv.y), pk2(bv.z, bv.w));
    }
  }
  __syncthreads();

  floatx4 acc[4][4];

  // GEMM over nkt K-chunks of 32; B ping-pong double-buffered (no reg copies).
  auto gemm = [&](const short8* wbase, int nkt) {
#pragma unroll
    for (int mb = 0; mb < 4; ++mb)
#pragma unroll
      for (int i = 0; i < 4; ++i) acc[mb][i] = (floatx4)(0.f);
    const short8* wp = wbase + w * 256 + l;
    short8 b0[4], b1v[4];
#pragma unroll
    for (int i = 0; i < 4; ++i) b0[i] = wp[i * 64];
    auto step = [&](const short8* bc, int ktt) {
      short8 af[4];
#pragma unroll
      for (int mb = 0; mb < 4; ++mb)
        af[mb] = *(const short8*)(smA + (mb * 16 + l16) * AROW + ktt * 64 + quad * 16);
#pragma unroll
      for (int mb = 0; mb < 4; ++mb)
#pragma unroll
        for (int i = 0; i < 4; ++i)
          acc[mb][i] = __builtin_amdgcn_mfma_f32_16x16x32_bf16(af[mb], bc[i],
                                                               acc[mb][i], 0, 0, 0);
    };
    int kt = 0;
    while (kt + 2 <= nkt) {
#pragma unroll
      for (int i = 0; i < 4; ++i) b1v[i] = wp[(size_t)(kt + 1) * 2048 + i * 64];
      step(b0, kt);
      int k2 = (kt + 2 < nkt) ? kt + 2 : nkt - 1;   // last pair: harmless reload
#pragma unroll
      for (int i = 0; i < 4; ++i) b0[i] = wp[(size_t)k2 * 2048 + i * 64];
      step(b1v, kt + 1);
      kt += 2;
    }
    if (kt < nkt) step(b0, kt);
  };

  // bias + PReLU + bf16 pair-pack (shfl_xor 1) + write back into A buffer
  auto epi_store = [&](const float* bias, const float* slope) {
    float bb[4], aa[4];
#pragma unroll
    for (int i = 0; i < 4; ++i) {
      int col = w * 64 + i * 16 + l16;
      bb[i] = bias[col];
      aa[i] = slope[col];
    }
    __syncthreads();   // everyone done READING A before we overwrite
#pragma unroll
    for (int mb = 0; mb < 4; ++mb) {
#pragma unroll
      for (int i = 0; i < 4; ++i) {
        unsigned dw[4];
#pragma unroll
        for (int r = 0; r < 4; ++r) {
          float v = acc[mb][i][r] + bb[i];
          v = v >= 0.f ? v : aa[i] * v;
          float o  = __shfl_xor(v, 1, 64);
          float lo = (l16 & 1) ? o : v;
          float hi = (l16 & 1) ? v : o;
          dw[r] = pk2(lo, hi);
        }
        int col2  = w * 64 + i * 16 + (l16 & ~1);
        int rbase = (l16 & 1) * 2;                 // even lanes rows 0,1; odd 2,3
#pragma unroll
        for (int rr = 0; rr < 2; ++rr) {
          int row = mb * 16 + quad * 4 + rbase + rr;
          *(unsigned*)(smA + row * AROW + col2 * 2) = dw[rbase + rr];
        }
      }
    }
    __syncthreads();
  };

  // ---- layer 1: K = 288 (9 chunks) ----
  gemm(wcat + (size_t)e * 9 * 2048, 9);
  epi_store(b1 + (size_t)e * H_SZ, a1 + (size_t)e * H_SZ);
  // ---- hidden layer 0: K = 512 (16 chunks) ----
  gemm(whf + (size_t)e * 16 * 2048, 16);
  epi_store(bh + (size_t)e * H_SZ, ah + (size_t)e * H_SZ);
  // ---- hidden layer 1 + fused output dot (fp32, no bf16 rounding) ----
  gemm(whf + (size_t)(E_SZ + e) * 16 * 2048, 16);
  {
    float bb[4], aa[4], wo[4];
#pragma unroll
    for (int i = 0; i < 4; ++i) {
      int col = w * 64 + i * 16 + l16;
      bb[i] = bh[(size_t)(E_SZ + e) * H_SZ + col];
      aa[i] = ah[(size_t)(E_SZ + e) * H_SZ + col];
      wo[i] = Wo[(size_t)e * H_SZ + col];
    }
    float ps[4][4];
#pragma unroll
    for (int mb = 0; mb < 4; ++mb)
#pragma unroll
      for (int r = 0; r < 4; ++r) ps[mb][r] = 0.f;
#pragma unroll
    for (int mb = 0; mb < 4; ++mb)
#pragma unroll
      for (int i = 0; i < 4; ++i)
#pragma unroll
        for (int r = 0; r < 4; ++r) {
          float v = acc[mb][i][r] + bb[i];
          v = v >= 0.f ? v : aa[i] * v;
          ps[mb][r] += v * wo[i];
        }
    // reduce over the 16 lanes of each quad (cols within this wave's slice)
#pragma unroll
    for (int d = 1; d < 16; d <<= 1)
#pragma unroll
      for (int mb = 0; mb < 4; ++mb)
#pragma unroll
        for (int r = 0; r < 4; ++r) ps[mb][r] += __shfl_xor(ps[mb][r], d, 64);
    __syncthreads();                 // done reading A; reuse its storage
    float* scratch = (float*)smA;    // [64 rows][8 waves]
    if (l16 == 0) {
#pragma unroll
      for (int mb = 0; mb < 4; ++mb)
#pragma unroll
        for (int r = 0; r < 4; ++r)
          scratch[(mb * 16 + quad * 4 + r) * 8 + w] = ps[mb][r];
    }
    __syncthreads();
    if (tid < BM) {
      float s = 0.f;
#pragma unroll
      for (int ww = 0; ww < 8; ++ww) s += scratch[tid * 8 + ww];
      out[(size_t)(m0 + tid) * E_SZ + e] = s + bo[e];
    }
  }
}

// ---------------------------------------------------------------------------
extern "C" void kernel_launch(void* const* d_in, const int* in_sizes, int n_in,
                              void* d_out, int out_size, void* d_ws, size_t ws_size,
                              hipStream_t stream) {
  const float* theta = (const float*)d_in[0];
  const float* x     = (const float*)d_in[1];
  const int*   masks = (const int*)d_in[2];
  const float* W1t   = (const float*)d_in[3];
  const float* W1x   = (const float*)d_in[4];
  const float* b1    = (const float*)d_in[5];
  const float* a1    = (const float*)d_in[6];
  const float* Wh    = (const float*)d_in[7];
  const float* bh    = (const float*)d_in[8];
  const float* ah    = (const float*)d_in[9];
  const float* Wo    = (const float*)d_in[10];
  const float* bo    = (const float*)d_in[11];
  float* out = (float*)d_out;

  // ws layout: [0, 9.4MB) layer-1 frags; [9.4MB, 43MB) hidden frags.
  uint4* wcat = (uint4*)d_ws;
  uint4* whf  = (uint4*)((char*)d_ws + (size_t)E_SZ * 9 * 2048 * 16);

  prep2_kernel<<<1312, 256, 0, stream>>>(W1t, W1x, masks, Wh, wcat, whf);
  mlp_kernel<<<2048, 512, 0, stream>>>(theta, x, (const short8*)wcat,
                                       (const short8*)whf, b1, a1, bh, ah, Wo, bo,
                                       out);
}

// Round 3
// 334.364 us; speedup vs baseline: 1.0456x; 1.0456x over previous
//
#include <hip/hip_runtime.h>
#include <stdint.h>

// Problem constants (from reference): B,T,X,E,H,L = 4096,32,256,32,512,2
#define B_SZ 4096
#define T_SZ 32
#define X_SZ 256
#define E_SZ 32
#define H_SZ 512
#define BM   64      // batch rows per block
// A-tile LDS row stride: 512 bf16 = 1024B, +16B pad -> conflict-free ds_read_b128
#define AROW 1040

typedef __attribute__((ext_vector_type(8))) short  short8;   // 8 bf16 = 4 VGPR
typedef __attribute__((ext_vector_type(4))) float  floatx4;

__device__ __forceinline__ unsigned short f2bf(float f) {
  unsigned u = __float_as_uint(f);
  u += 0x7fffu + ((u >> 16) & 1u);          // RNE (inputs finite, no NaN care)
  return (unsigned short)(u >> 16);
}
__device__ __forceinline__ unsigned pk2(float a, float b) {
  return (unsigned)f2bf(a) | ((unsigned)f2bf(b) << 16);
}

// ---------------------------------------------------------------------------
// Prep v3: coalesced + XCD-co-located with the mlp consumer.
// Grid 1312 = 8 XCDs x 164 chunks. bid&7 = XCD x -> owns experts 4x..4x+3.
// j = bid>>3: sub-expert written in order sub=3,2,1,0 (phase-0 expert last =
// freshest in that XCD's L2 when mlp phase 0 starts). Chunk c in [0,41):
// c<9 -> layer-1 cat chunk kt=c (kt==0 is the masked W1t rows), else hidden
// (le=(c-9)>>4, kt=(c-9)&15).
// Stage 32k x 512n fp32 -> bf16 LDS tile (pitch 524 ushort; staging & gather
// are 2-way bank aliasing = free), then gather MFMA B-fragment units:
//   unit u: nb=u>>6, l=u&63 -> n=nb*16+(l&15), k0=(l>>4)*8; 8 bf16 along k.
// Output layout identical to R0/R1 prep, so mlp_kernel is unchanged by this.
// ---------------------------------------------------------------------------
#define LPITCH 524   // ushorts per LDS row

__global__ __launch_bounds__(256) void prep3_kernel(
    const float* __restrict__ W1t, const float* __restrict__ W1x,
    const int* __restrict__ masks, const float* __restrict__ Wh,
    uint4* __restrict__ wcat, uint4* __restrict__ whf) {
  __shared__ unsigned short lds[32 * LPITCH];   // 33536 B
  const int bid = blockIdx.x, t = threadIdx.x;
  const int x   = bid & 7, j = bid >> 3;
  const int q41 = j / 41;                 // 0..3
  const int c   = j - q41 * 41;           // chunk within expert, 0..40
  const int e   = x * 4 + (3 - q41);      // phase-0 expert written LAST
  float4 v[16];
  if (c < 9) {                            // layer-1 cat matrix chunk kt=c
#pragma unroll
    for (int p = 0; p < 16; ++p) {
      int f  = p * 256 + t;               // float4 index within 32x512 tile
      int kk = f >> 7, n = (f & 127) * 4;
      int k  = c * 32 + kk;
      if (k < T_SZ) {
        v[p] = *(const float4*)(W1t + ((size_t)e * T_SZ + k) * H_SZ + n);
        float m = (float)masks[e * T_SZ + k];
        v[p].x *= m; v[p].y *= m; v[p].z *= m; v[p].w *= m;
      } else {
        v[p] = *(const float4*)(W1x + ((size_t)e * X_SZ + (k - T_SZ)) * H_SZ + n);
      }
    }
  } else {
    int h = c - 9, le = h >> 4, kt = h & 15;
    const float* base = Wh + (size_t)(le * E_SZ + e) * H_SZ * H_SZ +
                        (size_t)kt * 32 * H_SZ;
#pragma unroll
    for (int p = 0; p < 16; ++p) {
      int f  = p * 256 + t;
      int kk = f >> 7, n = (f & 127) * 4;
      v[p] = *(const float4*)(base + (size_t)kk * H_SZ + n);
    }
  }
#pragma unroll
  for (int p = 0; p < 16; ++p) {
    int f  = p * 256 + t;
    int kk = f >> 7, n = (f & 127) * 4;
    *(uint2*)&lds[kk * LPITCH + n] =
        make_uint2(pk2(v[p].x, v[p].y), pk2(v[p].z, v[p].w));
  }
  __syncthreads();
  uint4* dst = (c < 9)
                   ? (wcat + ((size_t)e * 9 + c) * 2048)
                   : (whf + ((size_t)(((c - 9) >> 4) * E_SZ + e) * 16 +
                             ((c - 9) & 15)) * 2048);
#pragma unroll 2
  for (int p = 0; p < 8; ++p) {
    int u  = p * 256 + t;
    int nb = u >> 6, l = u & 63;
    int n  = nb * 16 + (l & 15);
    int k0 = (l >> 4) * 8;
    unsigned d[4];
#pragma unroll
    for (int jj = 0; jj < 4; ++jj) {
      unsigned lo = lds[(k0 + 2 * jj)     * LPITCH + n];
      unsigned hi = lds[(k0 + 2 * jj + 1) * LPITCH + n];
      d[jj] = lo | (hi << 16);
    }
    dst[u] = make_uint4(d[0], d[1], d[2], d[3]);
  }
}

// ---------------------------------------------------------------------------
// Fused MLP: block = (64-row batch tile, expert e). 8 waves; wave w owns
// cols [64w,64w+64). acc 4x4 tiles of mfma_f32_16x16x32_bf16.
// A (activations) in LDS bf16, weights direct-from-global (fragment order).
// Block mapping: XCD (bid&7) processes its 4 experts in sequential phases
// (bid>>9); per-phase weight working set 1.3MB stays L2-resident.
// ---------------------------------------------------------------------------
__global__ __launch_bounds__(512, 4) void mlp_kernel(
    const float* __restrict__ theta, const float* __restrict__ x,
    const short8* __restrict__ wcat, const short8* __restrict__ whf,
    const float* __restrict__ b1, const float* __restrict__ a1,
    const float* __restrict__ bh, const float* __restrict__ ah,
    const float* __restrict__ Wo, const float* __restrict__ bo,
    float* __restrict__ out) {
  __shared__ __align__(16) char smA[BM * AROW];   // 66560 B
  const int tid = threadIdx.x;
  const int bid = blockIdx.x;
  const int e   = (bid & 7) * 4 + (bid >> 9);     // XCD-phase expert schedule
  const int m0  = ((bid >> 3) & 63) * BM;
  const int w   = tid >> 6, l = tid & 63, l16 = l & 15, quad = l >> 4;

  // ---- stage A0 = [theta | x] as bf16 (mask folded into prepped W1t) ----
  {
    int r = tid >> 3, c = tid & 7;                // 8 threads per row
    float4 th = *(const float4*)(theta + (size_t)(m0 + r) * T_SZ + c * 4);
    *(uint2*)(smA + r * AROW + c * 8) = make_uint2(pk2(th.x, th.y), pk2(th.z, th.w));
    const float4* xp = (const float4*)(x + (size_t)(m0 + r) * X_SZ);
#pragma unroll
    for (int q = 0; q < 4; ++q) {
      int ch = q * 8 + c;                         // interleave: conflict-free banks
      float4 a = xp[ch * 2], bv = xp[ch * 2 + 1];
      *(uint4*)(smA + r * AROW + 64 + ch * 16) =
          make_uint4(pk2(a.x, a.y), pk2(a.z, a.w), pk2(bv.x, bv.y), pk2(bv.z, bv.w));
    }
  }
  __syncthreads();

  floatx4 acc[4][4];

  // GEMM over nkt K-chunks of 32; B ping-pong double-buffered (no reg copies).
  auto gemm = [&](const short8* wbase, int nkt) {
#pragma unroll
    for (int mb = 0; mb < 4; ++mb)
#pragma unroll
      for (int i = 0; i < 4; ++i) acc[mb][i] = (floatx4)(0.f);
    const short8* wp = wbase + w * 256 + l;
    short8 b0[4], b1v[4];
#pragma unroll
    for (int i = 0; i < 4; ++i) b0[i] = wp[i * 64];
    auto step = [&](const short8* bc, int ktt) {
      short8 af[4];
#pragma unroll
      for (int mb = 0; mb < 4; ++mb)
        af[mb] = *(const short8*)(smA + (mb * 16 + l16) * AROW + ktt * 64 + quad * 16);
#pragma unroll
      for (int mb = 0; mb < 4; ++mb)
#pragma unroll
        for (int i = 0; i < 4; ++i)
          acc[mb][i] = __builtin_amdgcn_mfma_f32_16x16x32_bf16(af[mb], bc[i],
                                                               acc[mb][i], 0, 0, 0);
    };
    int kt = 0;
    while (kt + 2 <= nkt) {
#pragma unroll
      for (int i = 0; i < 4; ++i) b1v[i] = wp[(size_t)(kt + 1) * 2048 + i * 64];
      step(b0, kt);
      int k2 = (kt + 2 < nkt) ? kt + 2 : nkt - 1;   // last pair: harmless reload
#pragma unroll
      for (int i = 0; i < 4; ++i) b0[i] = wp[(size_t)k2 * 2048 + i * 64];
      step(b1v, kt + 1);
      kt += 2;
    }
    if (kt < nkt) step(b0, kt);
  };

  // bias + PReLU + bf16 pair-pack (shfl_xor 1) + write back into A buffer
  auto epi_store = [&](const float* bias, const float* slope) {
    float bb[4], aa[4];
#pragma unroll
    for (int i = 0; i < 4; ++i) {
      int col = w * 64 + i * 16 + l16;
      bb[i] = bias[col];
      aa[i] = slope[col];
    }
    __syncthreads();   // everyone done READING A before we overwrite
#pragma unroll
    for (int mb = 0; mb < 4; ++mb) {
#pragma unroll
      for (int i = 0; i < 4; ++i) {
        unsigned dw[4];
#pragma unroll
        for (int r = 0; r < 4; ++r) {
          float v = acc[mb][i][r] + bb[i];
          v = v >= 0.f ? v : aa[i] * v;
          float o  = __shfl_xor(v, 1, 64);
          float lo = (l16 & 1) ? o : v;
          float hi = (l16 & 1) ? v : o;
          dw[r] = pk2(lo, hi);
        }
        int col2  = w * 64 + i * 16 + (l16 & ~1);
        int rbase = (l16 & 1) * 2;                 // even lanes rows 0,1; odd 2,3
#pragma unroll
        for (int rr = 0; rr < 2; ++rr) {
          int row = mb * 16 + quad * 4 + rbase + rr;
          *(unsigned*)(smA + row * AROW + col2 * 2) = dw[rbase + rr];
        }
      }
    }
    __syncthreads();
  };

  // ---- layer 1: K = 288 (9 chunks) ----
  gemm(wcat + (size_t)e * 9 * 2048, 9);
  epi_store(b1 + (size_t)e * H_SZ, a1 + (size_t)e * H_SZ);
  // ---- hidden layer 0: K = 512 (16 chunks) ----
  gemm(whf + (size_t)e * 16 * 2048, 16);
  epi_store(bh + (size_t)e * H_SZ, ah + (size_t)e * H_SZ);
  // ---- hidden layer 1 + fused output dot (fp32, no bf16 rounding) ----
  gemm(whf + (size_t)(E_SZ + e) * 16 * 2048, 16);
  {
    float bb[4], aa[4], wo[4];
#pragma unroll
    for (int i = 0; i < 4; ++i) {
      int col = w * 64 + i * 16 + l16;
      bb[i] = bh[(size_t)(E_SZ + e) * H_SZ + col];
      aa[i] = ah[(size_t)(E_SZ + e) * H_SZ + col];
      wo[i] = Wo[(size_t)e * H_SZ + col];
    }
    float ps[4][4];
#pragma unroll
    for (int mb = 0; mb < 4; ++mb)
#pragma unroll
      for (int r = 0; r < 4; ++r) ps[mb][r] = 0.f;
#pragma unroll
    for (int mb = 0; mb < 4; ++mb)
#pragma unroll
      for (int i = 0; i < 4; ++i)
#pragma unroll
        for (int r = 0; r < 4; ++r) {
          float v = acc[mb][i][r] + bb[i];
          v = v >= 0.f ? v : aa[i] * v;
          ps[mb][r] += v * wo[i];
        }
    // reduce over the 16 lanes of each quad (cols within this wave's slice)
#pragma unroll
    for (int d = 1; d < 16; d <<= 1)
#pragma unroll
      for (int mb = 0; mb < 4; ++mb)
#pragma unroll
        for (int r = 0; r < 4; ++r) ps[mb][r] += __shfl_xor(ps[mb][r], d, 64);
    __syncthreads();                 // done reading A; reuse its storage
    float* scratch = (float*)smA;    // [64 rows][8 waves]
    if (l16 == 0) {
#pragma unroll
      for (int mb = 0; mb < 4; ++mb)
#pragma unroll
        for (int r = 0; r < 4; ++r)
          scratch[(mb * 16 + quad * 4 + r) * 8 + w] = ps[mb][r];
    }
    __syncthreads();
    if (tid < BM) {
      float s = 0.f;
#pragma unroll
      for (int ww = 0; ww < 8; ++ww) s += scratch[tid * 8 + ww];
      out[(size_t)(m0 + tid) * E_SZ + e] = s + bo[e];
    }
  }
}

// ---------------------------------------------------------------------------
extern "C" void kernel_launch(void* const* d_in, const int* in_sizes, int n_in,
                              void* d_out, int out_size, void* d_ws, size_t ws_size,
                              hipStream_t stream) {
  const float* theta = (const float*)d_in[0];
  const float* x     = (const float*)d_in[1];
  const int*   masks = (const int*)d_in[2];
  const float* W1t   = (const float*)d_in[3];
  const float* W1x   = (const float*)d_in[4];
  const float* b1    = (const float*)d_in[5];
  const float* a1    = (const float*)d_in[6];
  const float* Wh    = (const float*)d_in[7];
  const float* bh    = (const float*)d_in[8];
  const float* ah    = (const float*)d_in[9];
  const float* Wo    = (const float*)d_in[10];
  const float* bo    = (const float*)d_in[11];
  float* out = (float*)d_out;

  // ws layout: [0, 9.4MB) layer-1 frags; [9.4MB, 43MB) hidden frags.
  uint4* wcat = (uint4*)d_ws;
  uint4* whf  = (uint4*)((char*)d_ws + (size_t)E_SZ * 9 * 2048 * 16);

  prep3_kernel<<<1312, 256, 0, stream>>>(W1t, W1x, masks, Wh, wcat, whf);
  mlp_kernel<<<2048, 512, 0, stream>>>(theta, x, (const short8*)wcat,
                                       (const short8*)whf, b1, a1, bh, ah, Wo, bo,
                                       out);
}

// Round 4
// 326.153 us; speedup vs baseline: 1.0719x; 1.0252x over previous
//
#include <hip/hip_runtime.h>
#include <stdint.h>

// Problem constants (from reference): B,T,X,E,H,L = 4096,32,256,32,512,2
#define B_SZ 4096
#define T_SZ 32
#define X_SZ 256
#define E_SZ 32
#define H_SZ 512
#define BM   64      // batch rows per block
// A-tile LDS row stride: 512 bf16 = 1024B, +16B pad -> conflict-free ds_read_b128
#define AROW 1040
#define D_SZ 288     // T+X

typedef __attribute__((ext_vector_type(8))) short  short8;   // 8 bf16 = 4 VGPR
typedef __attribute__((ext_vector_type(4))) float  floatx4;

__device__ __forceinline__ unsigned short f2bf(float f) {
  unsigned u = __float_as_uint(f);
  u += 0x7fffu + ((u >> 16) & 1u);          // RNE (inputs finite, no NaN care)
  return (unsigned short)(u >> 16);
}
__device__ __forceinline__ unsigned pk2(float a, float b) {
  return (unsigned)f2bf(a) | ((unsigned)f2bf(b) << 16);
}

// ---------------------------------------------------------------------------
// Prep v4: coalesced, XCD-co-located weight fragments + bf16 activation cat.
// Blocks [0,1312): weights. bid&7 = XCD x -> experts 4x..4x+3; within an XCD
// expert 4x+3 written first, 4x+0 last (phase-0 expert freshest in L2).
// Chunk c<9: layer-1 cat (kt=c; k<32 rows are masked W1t), else hidden.
// Stage 32k x 512n fp32 -> bf16 LDS (pitch 524 ushort, 2-way = free), gather
// MFMA B-fragment units: u: nb=u>>6, l=u&63 -> n=nb*16+(l&15), k0=(l>>4)*8.
// Blocks [1312,1376): tx[r][0:288) = bf16([theta[r] | x[r]]), row-major.
// ---------------------------------------------------------------------------
#define LPITCH 524   // ushorts per LDS row

__global__ __launch_bounds__(256) void prep4_kernel(
    const float* __restrict__ W1t, const float* __restrict__ W1x,
    const int* __restrict__ masks, const float* __restrict__ Wh,
    const float* __restrict__ theta, const float* __restrict__ x,
    uint4* __restrict__ wcat, uint4* __restrict__ whf,
    unsigned short* __restrict__ tx) {
  const int bid = blockIdx.x, t = threadIdx.x;
  if (bid >= 1312) {                      // ---- activation conversion ----
    int g = bid - 1312;
    int r = g * 64 + (t >> 2), c = t & 3; // 4 threads per row
    // theta: 32 floats/row, thread handles 8 -> 1 uint4 out
    {
      float4 a = *(const float4*)(theta + (size_t)r * T_SZ + c * 8);
      float4 b = *(const float4*)(theta + (size_t)r * T_SZ + c * 8 + 4);
      *(uint4*)(tx + (size_t)r * D_SZ + c * 8) =
          make_uint4(pk2(a.x, a.y), pk2(a.z, a.w), pk2(b.x, b.y), pk2(b.z, b.w));
    }
    // x: 256 floats/row, thread handles 64 -> 8 uint4 out
#pragma unroll
    for (int j = 0; j < 8; ++j) {
      float4 a = *(const float4*)(x + (size_t)r * X_SZ + c * 64 + j * 8);
      float4 b = *(const float4*)(x + (size_t)r * X_SZ + c * 64 + j * 8 + 4);
      *(uint4*)(tx + (size_t)r * D_SZ + T_SZ + c * 64 + j * 8) =
          make_uint4(pk2(a.x, a.y), pk2(a.z, a.w), pk2(b.x, b.y), pk2(b.z, b.w));
    }
    return;
  }
  __shared__ unsigned short lds[32 * LPITCH];   // 33536 B
  const int xcd = bid & 7, j = bid >> 3;
  const int q41 = j / 41;                 // 0..3
  const int c   = j - q41 * 41;           // chunk within expert, 0..40
  const int e   = xcd * 4 + (3 - q41);    // phase-0 expert written LAST
  float4 v[16];
  if (c < 9) {                            // layer-1 cat matrix chunk kt=c
#pragma unroll
    for (int p = 0; p < 16; ++p) {
      int f  = p * 256 + t;               // float4 index within 32x512 tile
      int kk = f >> 7, n = (f & 127) * 4;
      int k  = c * 32 + kk;
      if (k < T_SZ) {
        v[p] = *(const float4*)(W1t + ((size_t)e * T_SZ + k) * H_SZ + n);
        float m = (float)masks[e * T_SZ + k];
        v[p].x *= m; v[p].y *= m; v[p].z *= m; v[p].w *= m;
      } else {
        v[p] = *(const float4*)(W1x + ((size_t)e * X_SZ + (k - T_SZ)) * H_SZ + n);
      }
    }
  } else {
    int h = c - 9, le = h >> 4, kt = h & 15;
    const float* base = Wh + (size_t)(le * E_SZ + e) * H_SZ * H_SZ +
                        (size_t)kt * 32 * H_SZ;
#pragma unroll
    for (int p = 0; p < 16; ++p) {
      int f  = p * 256 + t;
      int kk = f >> 7, n = (f & 127) * 4;
      v[p] = *(const float4*)(base + (size_t)kk * H_SZ + n);
    }
  }
#pragma unroll
  for (int p = 0; p < 16; ++p) {
    int f  = p * 256 + t;
    int kk = f >> 7, n = (f & 127) * 4;
    *(uint2*)&lds[kk * LPITCH + n] =
        make_uint2(pk2(v[p].x, v[p].y), pk2(v[p].z, v[p].w));
  }
  __syncthreads();
  uint4* dst = (c < 9)
                   ? (wcat + ((size_t)e * 9 + c) * 2048)
                   : (whf + ((size_t)(((c - 9) >> 4) * E_SZ + e) * 16 +
                             ((c - 9) & 15)) * 2048);
#pragma unroll 2
  for (int p = 0; p < 8; ++p) {
    int u  = p * 256 + t;
    int nb = u >> 6, l = u & 63;
    int n  = nb * 16 + (l & 15);
    int k0 = (l >> 4) * 8;
    unsigned d[4];
#pragma unroll
    for (int jj = 0; jj < 4; ++jj) {
      unsigned lo = lds[(k0 + 2 * jj)     * LPITCH + n];
      unsigned hi = lds[(k0 + 2 * jj + 1) * LPITCH + n];
      d[jj] = lo | (hi << 16);
    }
    dst[u] = make_uint4(d[0], d[1], d[2], d[3]);
  }
}

// ---------------------------------------------------------------------------
// GEMM over NKT K-chunks of 32 (compile-time, fully unrolled ping-pong).
// ---------------------------------------------------------------------------
template <int NKT>
__device__ __forceinline__ void gemm_run(const char* smA, const short8* wp,
                                         int l16, int quad,
                                         floatx4 (&acc)[4][4]) {
#pragma unroll
  for (int mb = 0; mb < 4; ++mb)
#pragma unroll
    for (int i = 0; i < 4; ++i) acc[mb][i] = (floatx4)(0.f);
  short8 buf[2][4];
#pragma unroll
  for (int i = 0; i < 4; ++i) buf[0][i] = wp[i * 64];
#pragma unroll
  for (int kt = 0; kt < NKT; ++kt) {
    int nk = (kt + 1 < NKT) ? kt + 1 : kt;      // last step: harmless reload
    short8* nb = buf[(kt + 1) & 1];
#pragma unroll
    for (int i = 0; i < 4; ++i) nb[i] = wp[(size_t)nk * 2048 + i * 64];
    short8 af[4];
#pragma unroll
    for (int mb = 0; mb < 4; ++mb)
      af[mb] = *(const short8*)(smA + (mb * 16 + l16) * AROW + kt * 64 + quad * 16);
    const short8* cb = buf[kt & 1];
#pragma unroll
    for (int mb = 0; mb < 4; ++mb)
#pragma unroll
      for (int i = 0; i < 4; ++i)
        acc[mb][i] = __builtin_amdgcn_mfma_f32_16x16x32_bf16(af[mb], cb[i],
                                                             acc[mb][i], 0, 0, 0);
  }
}

// ---------------------------------------------------------------------------
// Fused MLP, one phase (one expert per XCD): grid 512 = 64 m-tiles x 8 XCDs.
// e = (bid&7)*4 + phase; per-XCD concurrent weight set = 1.34MB < 4MiB L2.
// 8 waves; wave w owns cols [64w,64w+64); acc 4x4 of mfma_f32_16x16x32_bf16.
// ---------------------------------------------------------------------------
__global__ __launch_bounds__(512, 4) void mlp_kernel(
    const unsigned short* __restrict__ tx,
    const short8* __restrict__ wcat, const short8* __restrict__ whf,
    const float* __restrict__ b1, const float* __restrict__ a1,
    const float* __restrict__ bh, const float* __restrict__ ah,
    const float* __restrict__ Wo, const float* __restrict__ bo,
    float* __restrict__ out, int phase) {
  __shared__ __align__(16) char smA[BM * AROW];   // 66560 B
  const int tid = threadIdx.x;
  const int bid = blockIdx.x;
  const int e   = (bid & 7) * 4 + phase;          // one expert per XCD
  const int m0  = (bid >> 3) * BM;
  const int w   = tid >> 6, l = tid & 63, l16 = l & 15, quad = l >> 4;

  // ---- stage A0 = bf16 [theta|x] rows (pre-converted by prep) ----
  {
    int r = tid >> 3, c = tid & 7;                // 8 threads per row
    const unsigned short* src = tx + (size_t)(m0 + r) * D_SZ;
#pragma unroll
    for (int p = 0; p < 9; ++p)
      *(uint2*)(smA + r * AROW + 8 * (c + 8 * p)) =
          *(const uint2*)(src + 4 * (c + 8 * p));
  }
  __syncthreads();

  floatx4 acc[4][4];

  // bias + PReLU + bf16 pair-pack (shfl_xor 1) + write back into A buffer
  auto epi_store = [&](const float* bias, const float* slope) {
    float bb[4], aa[4];
#pragma unroll
    for (int i = 0; i < 4; ++i) {
      int col = w * 64 + i * 16 + l16;
      bb[i] = bias[col];
      aa[i] = slope[col];
    }
    __syncthreads();   // everyone done READING A before we overwrite
#pragma unroll
    for (int mb = 0; mb < 4; ++mb) {
#pragma unroll
      for (int i = 0; i < 4; ++i) {
        unsigned dw[4];
#pragma unroll
        for (int r = 0; r < 4; ++r) {
          float v = acc[mb][i][r] + bb[i];
          v = v >= 0.f ? v : aa[i] * v;
          float o  = __shfl_xor(v, 1, 64);
          float lo = (l16 & 1) ? o : v;
          float hi = (l16 & 1) ? v : o;
          dw[r] = pk2(lo, hi);
        }
        int col2  = w * 64 + i * 16 + (l16 & ~1);
        int rbase = (l16 & 1) * 2;                 // even lanes rows 0,1; odd 2,3
#pragma unroll
        for (int rr = 0; rr < 2; ++rr) {
          int row = mb * 16 + quad * 4 + rbase + rr;
          *(unsigned*)(smA + row * AROW + col2 * 2) = dw[rbase + rr];
        }
      }
    }
    __syncthreads();
  };

  const int woff = w * 256 + l;
  // ---- layer 1: K = 288 (9 chunks) ----
  gemm_run<9>(smA, wcat + (size_t)e * 9 * 2048 + woff, l16, quad, acc);
  epi_store(b1 + (size_t)e * H_SZ, a1 + (size_t)e * H_SZ);
  // ---- hidden layer 0: K = 512 (16 chunks) ----
  gemm_run<16>(smA, whf + (size_t)e * 16 * 2048 + woff, l16, quad, acc);
  epi_store(bh + (size_t)e * H_SZ, ah + (size_t)e * H_SZ);
  // ---- hidden layer 1 + fused output dot (fp32, no bf16 rounding) ----
  gemm_run<16>(smA, whf + (size_t)(E_SZ + e) * 16 * 2048 + woff, l16, quad, acc);
  {
    float bb[4], aa[4], wo[4];
#pragma unroll
    for (int i = 0; i < 4; ++i) {
      int col = w * 64 + i * 16 + l16;
      bb[i] = bh[(size_t)(E_SZ + e) * H_SZ + col];
      aa[i] = ah[(size_t)(E_SZ + e) * H_SZ + col];
      wo[i] = Wo[(size_t)e * H_SZ + col];
    }
    float ps[4][4];
#pragma unroll
    for (int mb = 0; mb < 4; ++mb)
#pragma unroll
      for (int r = 0; r < 4; ++r) ps[mb][r] = 0.f;
#pragma unroll
    for (int mb = 0; mb < 4; ++mb)
#pragma unroll
      for (int i = 0; i < 4; ++i)
#pragma unroll
        for (int r = 0; r < 4; ++r) {
          float v = acc[mb][i][r] + bb[i];
          v = v >= 0.f ? v : aa[i] * v;
          ps[mb][r] += v * wo[i];
        }
    // reduce over the 16 lanes of each quad (cols within this wave's slice)
#pragma unroll
    for (int d = 1; d < 16; d <<= 1)
#pragma unroll
      for (int mb = 0; mb < 4; ++mb)
#pragma unroll
        for (int r = 0; r < 4; ++r) ps[mb][r] += __shfl_xor(ps[mb][r], d, 64);
    __syncthreads();                 // done reading A; reuse its storage
    float* scratch = (float*)smA;    // [64 rows][8 waves]
    if (l16 == 0) {
#pragma unroll
      for (int mb = 0; mb < 4; ++mb)
#pragma unroll
        for (int r = 0; r < 4; ++r)
          scratch[(mb * 16 + quad * 4 + r) * 8 + w] = ps[mb][r];
    }
    __syncthreads();
    if (tid < BM) {
      float s = 0.f;
#pragma unroll
      for (int ww = 0; ww < 8; ++ww) s += scratch[tid * 8 + ww];
      out[(size_t)(m0 + tid) * E_SZ + e] = s + bo[e];
    }
  }
}

// ---------------------------------------------------------------------------
extern "C" void kernel_launch(void* const* d_in, const int* in_sizes, int n_in,
                              void* d_out, int out_size, void* d_ws, size_t ws_size,
                              hipStream_t stream) {
  const float* theta = (const float*)d_in[0];
  const float* x     = (const float*)d_in[1];
  const int*   masks = (const int*)d_in[2];
  const float* W1t   = (const float*)d_in[3];
  const float* W1x   = (const float*)d_in[4];
  const float* b1    = (const float*)d_in[5];
  const float* a1    = (const float*)d_in[6];
  const float* Wh    = (const float*)d_in[7];
  const float* bh    = (const float*)d_in[8];
  const float* ah    = (const float*)d_in[9];
  const float* Wo    = (const float*)d_in[10];
  const float* bo    = (const float*)d_in[11];
  float* out = (float*)d_out;

  // ws layout: [0, 9.4MB) layer-1 frags; [+33.5MB) hidden frags; [+2.4MB) tx.
  uint4* wcat = (uint4*)d_ws;
  uint4* whf  = (uint4*)((char*)d_ws + (size_t)E_SZ * 9 * 2048 * 16);
  unsigned short* tx =
      (unsigned short*)((char*)d_ws + (size_t)E_SZ * 9 * 2048 * 16 +
                        (size_t)2 * E_SZ * 16 * 2048 * 16);

  prep4_kernel<<<1376, 256, 0, stream>>>(W1t, W1x, masks, Wh, theta, x,
                                         wcat, whf, tx);
  for (int p = 0; p < 4; ++p)
    mlp_kernel<<<512, 512, 0, stream>>>(tx, (const short8*)wcat,
                                        (const short8*)whf, b1, a1, bh, ah, Wo,
                                        bo, out, p);
}